// Round 14
// baseline (152.631 us; speedup 1.0000x reference)
//
#include <hip/hip_runtime.h>
#include <math.h>

#define FF 512
#define EE 32
#define RS 40     // LDS row stride in bf16 elements (80 B: 2-way bank alias = free)
#define FCAP 416  // staged-row cap; cnt = 1+Binom(511,0.5), max over fixed inputs ~300
#define NTCAP 26  // FCAP/16

typedef __attribute__((ext_vector_type(8))) short bf16x8;
typedef __attribute__((ext_vector_type(4))) float f32x4;

// sqrt(1/sqrt(32) * log2(e)) — folded into staged FX so MFMA output is the exp2 arg
#define SFOLD 0.5050092f

__device__ __forceinline__ unsigned short f2bf(float x) {
    unsigned int u = __float_as_uint(x);
    return (unsigned short)((u + 0x7fffu + ((u >> 16) & 1u)) >> 16);
}

// accumulate Z (sum of e) and h (sum of e*g) from one C/D tile fragment
__device__ __forceinline__ void zh4(f32x4 d, float4 g, float& z, float& h) {
    float e0 = __builtin_amdgcn_exp2f(d[0]);
    float e1 = __builtin_amdgcn_exp2f(d[1]);
    float e2 = __builtin_amdgcn_exp2f(d[2]);
    float e3 = __builtin_amdgcn_exp2f(d[3]);
    z += (e0 + e1) + (e2 + e3);
    h = fmaf(e0, g.x, fmaf(e1, g.y, fmaf(e2, g.z, fmaf(e3, g.w, h))));
}

// ---- fused pass over NC contiguous q-column blocks, strip range [s_lo, s_hi);
// partial Z/h flushed to LDS via atomicAdd (two i-half waves share each column) ----
template <int NC>
__device__ __forceinline__ void fused(const unsigned short* __restrict__ myrow,
                                      const float* __restrict__ gs,
                                      float* __restrict__ Zp, float* __restrict__ Hp,
                                      int c0, int s_lo, int s_hi, int lane, int grp) {
    bf16x8 bf[NC];
#pragma unroll
    for (int c = 0; c < NC; ++c)
        bf[c] = *(const bf16x8*)(myrow + (size_t)(c0 + c) * 16 * RS);
    float z[NC], h[NC];
#pragma unroll
    for (int c = 0; c < NC; ++c) { z[c] = 0.f; h[c] = 0.f; }
    const unsigned short* ap = myrow + (size_t)s_lo * 16 * RS;
    const float* gp = gs + s_lo * 16 + grp * 4;
    int s = s_lo;
    for (; s + 2 <= s_hi; s += 2) {
        bf16x8 a0 = *(const bf16x8*)(ap);
        bf16x8 a1 = *(const bf16x8*)(ap + 16 * RS);
        ap += 32 * RS;
        float4 g0 = *(const float4*)(gp);
        float4 g1 = *(const float4*)(gp + 16);
        gp += 32;
#pragma unroll
        for (int c = 0; c < NC; ++c) {
            f32x4 d0 = {0.f, 0.f, 0.f, 0.f};
            f32x4 d1 = {0.f, 0.f, 0.f, 0.f};
            d0 = __builtin_amdgcn_mfma_f32_16x16x32_bf16(a0, bf[c], d0, 0, 0, 0);
            d1 = __builtin_amdgcn_mfma_f32_16x16x32_bf16(a1, bf[c], d1, 0, 0, 0);
            zh4(d0, g0, z[c], h[c]);
            zh4(d1, g1, z[c], h[c]);
        }
    }
    if (s < s_hi) {                   // single-strip tail (no pad strip staged)
        bf16x8 a0 = *(const bf16x8*)(ap);
        float4 g0 = *(const float4*)(gp);
#pragma unroll
        for (int c = 0; c < NC; ++c) {
            f32x4 d0 = {0.f, 0.f, 0.f, 0.f};
            d0 = __builtin_amdgcn_mfma_f32_16x16x32_bf16(a0, bf[c], d0, 0, 0, 0);
            zh4(d0, g0, z[c], h[c]);
        }
    }
#pragma unroll
    for (int c = 0; c < NC; ++c) {
        float zz = z[c], hh = h[c];
        zz += __shfl_xor(zz, 16); zz += __shfl_xor(zz, 32);
        hh += __shfl_xor(hh, 16); hh += __shfl_xor(hh, 32);
        if (lane < 16) {
            atomicAdd(&Zp[(c0 + c) * 16 + lane], zz);
            atomicAdd(&Hp[(c0 + c) * 16 + lane], hh);
        }
    }
}

// block=512 (8 waves); LDS ~39.4 KB -> 4 blocks/CU = 32 waves/CU (wave cap); VGPR cap 64
extern "C" __global__ void __launch_bounds__(512, 8)
model_kernel(const float* __restrict__ X, const float* __restrict__ Xi,
             const float* __restrict__ I, const float* __restrict__ S,
             const float* __restrict__ xi_w, const float* __restrict__ xi_b,
             const float* __restrict__ xs_w, const float* __restrict__ xs_b,
             float* __restrict__ out) {
    const int n = blockIdx.x;
    const int tid = threadIdx.x;
    const int lane = tid & 63;
    const int wv = tid >> 6;          // 8 waves per block
    const int l15 = lane & 15;
    const int grp = lane >> 4;

    __shared__ __align__(16) unsigned short fxb[FCAP * RS];  // 33280 B bf16 (scaled FX)
    __shared__ unsigned short lst[FF];                       // 1024 B
    __shared__ __align__(16) float gs[FCAP];                 // 1664 B: g_k = SFOLD*FX_k.Iw
    __shared__ __align__(16) float Zp[FCAP];                 // 1664 B: partial Z
    __shared__ __align__(16) float Hp[FCAP];                 // 1664 B: partial h
    __shared__ __align__(16) float idxb[EE];
    __shared__ __align__(16) float iw_sh[EE];
    __shared__ float a_sh;
    __shared__ int sh_idx;
    __shared__ int wbase[8];

    const float* Srow = S + (size_t)n * FF;
    const float* Irow = I + (size_t)n * FF;
    const float* Xrow = X + (size_t)n * FF;

    // one-hot scan + activity + accumulator zero-init (512 threads == FF)
    if (Irow[tid] > 0.5f) sh_idx = tid;
    if (tid < FCAP) { Zp[tid] = 0.f; Hp[tid] = 0.f; }
    if (tid == 0) a_sh = 0.f;
    bool act = Srow[tid] > 0.f;
    unsigned long long m = __ballot(act);
    int nb = __popcll(m & ((1ull << lane) - 1ull));
    if (lane == 0) wbase[wv] = __popcll(m);
    __syncthreads();

    int off = 0;
    for (int i = 0; i < wv; ++i) off += wbase[i];
    if (act) lst[off + nb] = (unsigned short)tid;   // order-preserving compaction
    int cntr = 0;
#pragma unroll
    for (int i = 0; i < 8; ++i) cntr += wbase[i];
    const int cnt = (cntr < FCAP) ? cntr : FCAP;     // defensive cap (never triggers)
    int nt0 = (cnt + 15) >> 4;
    const int nt = (nt0 < NTCAP) ? nt0 : NTCAP;      // 16x16 tiles per side
    const int ntp16 = nt * 16;                       // staged rows (no pair-pad strip)
    const int idx = sh_idx;
    if (tid < EE) {
        idxb[tid] = xs_b[idx * EE + tid];
        iw_sh[tid] = xi_w[idx * EE + tid];
    }
    __syncthreads();

    // ---- build scaled FX (compacted, bf16) into LDS (zero-pad last strip)
    // and fused g_k = sum_e (SFOLD*FX_k[e]) * Iw[e] via 8-lane shuffle reduce ----
    for (int jb = 0; jb < ntp16; jb += 64) {
        int j = jb + (tid >> 3);
        int e4 = (tid & 7) * 4;
        float part = 0.f;
        if (j < ntp16) {
            unsigned short h0 = 0, h1 = 0, h2 = 0, h3 = 0;
            if (j < cnt) {
                int f = lst[j];
                float xv = Xrow[f];
                float4 w4 = *(const float4*)(xs_w + f * EE + e4);
                float4 b4 = *(const float4*)(xs_b + f * EE + e4);
                float4 i4 = *(const float4*)(idxb + e4);
                float r0 = SFOLD * fmaf(xv, w4.x, b4.x + i4.x);
                float r1 = SFOLD * fmaf(xv, w4.y, b4.y + i4.y);
                float r2 = SFOLD * fmaf(xv, w4.z, b4.z + i4.z);
                float r3 = SFOLD * fmaf(xv, w4.w, b4.w + i4.w);
                h0 = f2bf(r0); h1 = f2bf(r1); h2 = f2bf(r2); h3 = f2bf(r3);
                const float* iw = iw_sh + e4;
                part = fmaf(r0, iw[0], fmaf(r1, iw[1], fmaf(r2, iw[2], r3 * iw[3])));
            }
            ushort4 pk = make_ushort4(h0, h1, h2, h3);
            *(ushort4*)(fxb + j * RS + e4) = pk;
        }
        part += __shfl_xor(part, 1);
        part += __shfl_xor(part, 2);
        part += __shfl_xor(part, 4);
        if ((tid & 7) == 0 && j < ntp16) gs[j] = part;   // g=0 for padded rows
    }
    __syncthreads();

    const unsigned short* myrow = fxb + (size_t)l15 * RS + grp * 8;
    const float pad = (float)(ntp16 - cnt);   // zero rows add exp2(0)=1 to each Z

    // 4 column groups x 2 i-halves = 8 waves, all active; NC=4 amortizes A/g reads
    const int cg = wv & 3;                 // column group
    const int ih = wv >> 2;                // i-half
    const int gbase = nt >> 2, grem = nt & 3;
    const int ncols = gbase + (cg < grem ? 1 : 0);
    int c0 = cg * gbase + (cg < grem ? cg : grem);
    const int shalf = nt >> 1;
    const int s_lo = ih ? shalf : 0;
    const int s_hi = ih ? nt : shalf;

    // ---- single fused pass: Z_q and h_q together, one exp per pair ----
    for (int done = 0; done < ncols; ) {
        int nc = ncols - done;
        if (nc >= 4)      { fused<4>(myrow, gs, Zp, Hp, c0 + done, s_lo, s_hi, lane, grp); done += 4; }
        else if (nc == 3) { fused<3>(myrow, gs, Zp, Hp, c0 + done, s_lo, s_hi, lane, grp); done += 3; }
        else if (nc == 2) { fused<2>(myrow, gs, Zp, Hp, c0 + done, s_lo, s_hi, lane, grp); done += 2; }
        else              { fused<1>(myrow, gs, Zp, Hp, c0 + done, s_lo, s_hi, lane, grp); done += 1; }
    }
    __syncthreads();

    // ---- final: a_sh = sum_q Hp[q] / (Zp[q]-pad) over q < cnt ----
    {
        float val = (tid < cnt) ? Hp[tid] / fmaxf(Zp[tid] - pad, 1e-9f) : 0.f;
        val += __shfl_xor(val, 1);
        val += __shfl_xor(val, 2);
        val += __shfl_xor(val, 4);
        val += __shfl_xor(val, 8);
        val += __shfl_xor(val, 16);
        val += __shfl_xor(val, 32);
        if (lane == 0) atomicAdd(&a_sh, val);
    }
    __syncthreads();

    // ---- epilogue: a = (sum_q h_q/Z_q) / (cnt * SFOLD); out = Xi*a - softplus(a)
    if (tid == 0) {
        float a = a_sh / ((float)cnt * SFOLD);
        float xiv = Xi[n];
        float mm = fmaxf(a, 0.f);
        float sp = mm + logf(__expf(a - mm) + __expf(-mm));
        out[n] = xiv * a - sp;  // b-terms cancel
    }
}

extern "C" void kernel_launch(void* const* d_in, const int* in_sizes, int n_in,
                              void* d_out, int out_size, void* d_ws, size_t ws_size,
                              hipStream_t stream) {
    const float* X    = (const float*)d_in[0];
    const float* Xi   = (const float*)d_in[1];
    const float* I    = (const float*)d_in[2];
    const float* S    = (const float*)d_in[3];
    const float* xi_w = (const float*)d_in[4];
    const float* xi_b = (const float*)d_in[5];
    const float* xs_w = (const float*)d_in[6];
    const float* xs_b = (const float*)d_in[7];
    float* out = (float*)d_out;
    const int N = in_sizes[1];  // Xi is [N]
    hipLaunchKernelGGL(model_kernel, dim3(N), dim3(512), 0, stream,
                       X, Xi, I, S, xi_w, xi_b, xs_w, xs_b, out);
}

// Round 15
// 104.331 us; speedup vs baseline: 1.4629x; 1.4629x over previous
//
#include <hip/hip_runtime.h>
#include <math.h>

#define FF 512
#define EE 32
#define RS 40     // LDS row stride in bf16 elements (80 B: 2-way bank alias = free)
#define FCAP 416  // staged-row cap; cnt = 1+Binom(511,0.5), max over fixed inputs ~300
#define NTCAP 26  // FCAP/16

typedef __attribute__((ext_vector_type(8))) short bf16x8;
typedef __attribute__((ext_vector_type(4))) float f32x4;

// sqrt(1/sqrt(32) * log2(e)) — folded into staged FX so MFMA output is the exp2 arg
#define SFOLD 0.5050092f

__device__ __forceinline__ unsigned short f2bf(float x) {
    unsigned int u = __float_as_uint(x);
    return (unsigned short)((u + 0x7fffu + ((u >> 16) & 1u)) >> 16);
}

// accumulate Z (sum of e) and h (sum of e*g) from one C/D tile fragment
__device__ __forceinline__ void zh4(f32x4 d, float4 g, float& z, float& h) {
    float e0 = __builtin_amdgcn_exp2f(d[0]);
    float e1 = __builtin_amdgcn_exp2f(d[1]);
    float e2 = __builtin_amdgcn_exp2f(d[2]);
    float e3 = __builtin_amdgcn_exp2f(d[3]);
    z += (e0 + e1) + (e2 + e3);
    h = fmaf(e0, g.x, fmaf(e1, g.y, fmaf(e2, g.z, fmaf(e3, g.w, h))));
}

// ---- fused pass over NC (<=2) contiguous q-column blocks owned by this wave:
// Z_q = sum_k e_qk ; h_q = sum_k e_qk * g_k ; emit sum_q h_q/(Z_q-pad).
// All MFMAs of an iteration are issued before any exp2 (4 independent chains). ----
template <int NC>
__device__ __forceinline__ void fused_cols(const unsigned short* __restrict__ myrow,
                                           const float* __restrict__ gs,
                                           float* __restrict__ a_sh,
                                           int c0, int nt, int cnt, float pad,
                                           int lane, int grp) {
    bf16x8 bf[NC];
#pragma unroll
    for (int c = 0; c < NC; ++c)
        bf[c] = *(const bf16x8*)(myrow + (size_t)(c0 + c) * 16 * RS);
    float zA[NC], zB[NC], hA[NC], hB[NC];
#pragma unroll
    for (int c = 0; c < NC; ++c) { zA[c] = 0.f; zB[c] = 0.f; hA[c] = 0.f; hB[c] = 0.f; }
    const unsigned short* ap = myrow;
    const float* gp = gs + grp * 4;
    int i = 0;
    for (; i + 2 <= nt; i += 2) {
        bf16x8 a0 = *(const bf16x8*)(ap);
        bf16x8 a1 = *(const bf16x8*)(ap + 16 * RS);
        ap += 32 * RS;
        float4 g0 = *(const float4*)(gp);
        float4 g1 = *(const float4*)(gp + 16);
        gp += 32;
        f32x4 d0[NC], d1[NC];
#pragma unroll
        for (int c = 0; c < NC; ++c) {       // issue all MFMAs first
            f32x4 zr = {0.f, 0.f, 0.f, 0.f};
            d0[c] = __builtin_amdgcn_mfma_f32_16x16x32_bf16(a0, bf[c], zr, 0, 0, 0);
            d1[c] = __builtin_amdgcn_mfma_f32_16x16x32_bf16(a1, bf[c], zr, 0, 0, 0);
        }
#pragma unroll
        for (int c = 0; c < NC; ++c) {       // then all exp/accumulate chains
            zh4(d0[c], g0, zA[c], hA[c]);
            zh4(d1[c], g1, zB[c], hB[c]);
        }
    }
    if (i < nt) {                            // single-strip tail
        bf16x8 a0 = *(const bf16x8*)(ap);
        float4 g0 = *(const float4*)(gp);
        f32x4 d0[NC];
#pragma unroll
        for (int c = 0; c < NC; ++c) {
            f32x4 zr = {0.f, 0.f, 0.f, 0.f};
            d0[c] = __builtin_amdgcn_mfma_f32_16x16x32_bf16(a0, bf[c], zr, 0, 0, 0);
        }
#pragma unroll
        for (int c = 0; c < NC; ++c)
            zh4(d0[c], g0, zA[c], hA[c]);
    }
#pragma unroll
    for (int c = 0; c < NC; ++c) {
        float z = zA[c] + zB[c];
        float h = hA[c] + hB[c];
        z += __shfl_xor(z, 16); z += __shfl_xor(z, 32);
        h += __shfl_xor(h, 16); h += __shfl_xor(h, 32);
        int q = (c0 + c) * 16 + lane;
        float val = (lane < 16 && q < cnt) ? h / fmaxf(z - pad, 1e-9f) : 0.f;
        val += __shfl_xor(val, 1);
        val += __shfl_xor(val, 2);
        val += __shfl_xor(val, 4);
        val += __shfl_xor(val, 8);
        if (lane == 0) atomicAdd(a_sh, val);
    }
}

// block=512 (8 waves); LDS ~36.5 KB -> 4 blocks/CU = 32 waves/CU (wave cap); VGPR cap 64
extern "C" __global__ void __launch_bounds__(512, 8)
model_kernel(const float* __restrict__ X, const float* __restrict__ Xi,
             const float* __restrict__ I, const float* __restrict__ S,
             const float* __restrict__ xi_w, const float* __restrict__ xi_b,
             const float* __restrict__ xs_w, const float* __restrict__ xs_b,
             float* __restrict__ out) {
    const int n = blockIdx.x;
    const int tid = threadIdx.x;
    const int lane = tid & 63;
    const int wv = tid >> 6;          // 8 waves per block
    const int l15 = lane & 15;
    const int grp = lane >> 4;

    __shared__ __align__(16) unsigned short fxb[FCAP * RS];  // 33280 B bf16 (scaled FX)
    __shared__ unsigned short lst[FF];                       // 1024 B
    __shared__ __align__(16) float gs[FCAP];                 // 1664 B: g_k = SFOLD*FX_k.Iw
    __shared__ __align__(16) float idxb[EE];
    __shared__ __align__(16) float iw_sh[EE];
    __shared__ float a_sh;
    __shared__ int sh_idx;
    __shared__ int wbase[8];

    const float* Srow = S + (size_t)n * FF;
    const float* Irow = I + (size_t)n * FF;
    const float* Xrow = X + (size_t)n * FF;

    // one-hot scan + activity (512 threads == FF)
    if (Irow[tid] > 0.5f) sh_idx = tid;
    bool act = Srow[tid] > 0.f;
    unsigned long long m = __ballot(act);
    int nb = __popcll(m & ((1ull << lane) - 1ull));
    if (lane == 0) wbase[wv] = __popcll(m);
    __syncthreads();

    int off = 0;
    for (int i = 0; i < wv; ++i) off += wbase[i];
    if (act) lst[off + nb] = (unsigned short)tid;   // order-preserving compaction
    int cntr = 0;
#pragma unroll
    for (int i = 0; i < 8; ++i) cntr += wbase[i];
    const int cnt = (cntr < FCAP) ? cntr : FCAP;     // defensive cap (never triggers)
    int nt0 = (cnt + 15) >> 4;
    const int nt = (nt0 < NTCAP) ? nt0 : NTCAP;      // 16x16 tiles per side
    const int ntp16 = nt * 16;
    const int jend = ((nt + 1) >> 1) * 32;           // staged rows padded to pair boundary
    const int idx = sh_idx;
    if (tid < EE) {
        idxb[tid] = xs_b[idx * EE + tid];
        iw_sh[tid] = xi_w[idx * EE + tid];
    }
    if (tid == 0) a_sh = 0.f;
    __syncthreads();

    // ---- build scaled FX (compacted, bf16) into LDS (zero-pad to pair boundary)
    // and fused g_k = sum_e (SFOLD*FX_k[e]) * Iw[e] via 8-lane shuffle reduce ----
    for (int jb = 0; jb < jend; jb += 64) {
        int j = jb + (tid >> 3);
        int e4 = (tid & 7) * 4;
        float part = 0.f;
        if (j < jend) {
            unsigned short h0 = 0, h1 = 0, h2 = 0, h3 = 0;
            if (j < cnt) {
                int f = lst[j];
                float xv = Xrow[f];
                float4 w4 = *(const float4*)(xs_w + f * EE + e4);
                float4 b4 = *(const float4*)(xs_b + f * EE + e4);
                float4 i4 = *(const float4*)(idxb + e4);
                float r0 = SFOLD * fmaf(xv, w4.x, b4.x + i4.x);
                float r1 = SFOLD * fmaf(xv, w4.y, b4.y + i4.y);
                float r2 = SFOLD * fmaf(xv, w4.z, b4.z + i4.z);
                float r3 = SFOLD * fmaf(xv, w4.w, b4.w + i4.w);
                h0 = f2bf(r0); h1 = f2bf(r1); h2 = f2bf(r2); h3 = f2bf(r3);
                const float* iw = iw_sh + e4;
                part = fmaf(r0, iw[0], fmaf(r1, iw[1], fmaf(r2, iw[2], r3 * iw[3])));
            }
            ushort4 pk = make_ushort4(h0, h1, h2, h3);
            *(ushort4*)(fxb + j * RS + e4) = pk;
        }
        part += __shfl_xor(part, 1);
        part += __shfl_xor(part, 2);
        part += __shfl_xor(part, 4);
        if ((tid & 7) == 0 && j < jend) gs[j] = part;   // g=0 for padded rows
    }
    __syncthreads();

    const unsigned short* myrow = fxb + (size_t)l15 * RS + grp * 8;
    // fused loop covers nt strips; only last-strip zeros contribute exp2(0)=1 to Z
    const float pad = (float)(ntp16 - cnt);

    // uneven contiguous column ownership (R9 scheme; TLP hides imbalance)
    const int cbase = nt >> 3, crem = nt & 7;
    const int ncols = cbase + (wv < crem ? 1 : 0);
    const int c0 = wv * cbase + (wv < crem ? wv : crem);

    // ---- single fused pass: Z_q and h_q together, one exp per pair; NC<=2 only
    // (NC>=3 under the 64-VGPR cap spills — measured R10/R14) ----
    switch (ncols) {
        case 1: fused_cols<1>(myrow, gs, &a_sh, c0, nt, cnt, pad, lane, grp); break;
        case 2: fused_cols<2>(myrow, gs, &a_sh, c0, nt, cnt, pad, lane, grp); break;
        case 3: fused_cols<2>(myrow, gs, &a_sh, c0, nt, cnt, pad, lane, grp);
                fused_cols<1>(myrow, gs, &a_sh, c0 + 2, nt, cnt, pad, lane, grp); break;
        case 4: fused_cols<2>(myrow, gs, &a_sh, c0, nt, cnt, pad, lane, grp);
                fused_cols<2>(myrow, gs, &a_sh, c0 + 2, nt, cnt, pad, lane, grp); break;
        default: break;  // ncols == 0 (tiny cnt only)
    }
    __syncthreads();

    // ---- epilogue: a = (sum_q h_q/Z_q) / (cnt * SFOLD); out = Xi*a - softplus(a)
    if (tid == 0) {
        float a = a_sh / ((float)cnt * SFOLD);
        float xiv = Xi[n];
        float mm = fmaxf(a, 0.f);
        float sp = mm + logf(__expf(a - mm) + __expf(-mm));
        out[n] = xiv * a - sp;  // b-terms cancel
    }
}

extern "C" void kernel_launch(void* const* d_in, const int* in_sizes, int n_in,
                              void* d_out, int out_size, void* d_ws, size_t ws_size,
                              hipStream_t stream) {
    const float* X    = (const float*)d_in[0];
    const float* Xi   = (const float*)d_in[1];
    const float* I    = (const float*)d_in[2];
    const float* S    = (const float*)d_in[3];
    const float* xi_w = (const float*)d_in[4];
    const float* xi_b = (const float*)d_in[5];
    const float* xs_w = (const float*)d_in[6];
    const float* xs_b = (const float*)d_in[7];
    float* out = (float*)d_out;
    const int N = in_sizes[1];  // Xi is [N]
    hipLaunchKernelGGL(model_kernel, dim3(N), dim3(512), 0, stream,
                       X, Xi, I, S, xi_w, xi_b, xs_w, xs_b, out);
}